// Round 5
// baseline (147.390 us; speedup 1.0000x reference)
//
#include <hip/hip_runtime.h>
#include <hip/hip_bf16.h>
#include <cstdint>
#include <cstddef>

// out = (A2 @ E^T) @ W^T, A2[i,j] = a[i-j] lower-tri Toeplitz,
//   a[d] = (d/4096 + 1e-8)^0.2, a[0] = 1e-8^0.2
// gemm_a: T[i,e] = sum_{j<=i} a[i-j] * E[e,j]  (tri, split-j -> T0 + T1)
// tsum:   Tsum = T0 + T1
// gemm_b: out[i,v] = sum_e Tsum[i,e] * W[v,e]
// Round 11 (DIAGNOSTIC): identical to R4 except gemm_a runs its K-pipeline
// TWICE into the same accumulator (epilogue scales by 0.5 -> exact same
// result, no DCE). Delta vs R4's 125.88us = gemm_a steady-state duration.
// Pre-committed: delta ~25-30 -> kernels match model, remainder is harness
// overhead (near floor); delta ~50-70 -> gemm_a has ~2x structural slack ->
// port to 8-phase counted-vmcnt next.

#define L_SER 4096
#define DEMB  1024
#define DV    1024

#define R_STRIDE 4224   // shift-replica stride of reversed a; 16B-aligned
#define R_O0     4096

typedef __bf16 bf16_t;
typedef __attribute__((ext_vector_type(8))) __bf16 bf16x8;
typedef __attribute__((ext_vector_type(4))) float f32x4;

// direct global->LDS async copy, 16B per lane (dest = uniform base + lane*16)
__device__ __forceinline__ void glds16(const bf16_t* g, bf16_t* l) {
    __builtin_amdgcn_global_load_lds(
        (const __attribute__((address_space(1))) unsigned int*)(const void*)g,
        (__attribute__((address_space(3))) unsigned int*)(void*)l,
        16, 0, 0);
}

// ---------------------------------------------------------------------------
// Fused prep: blocks [0,132) build R; [132,2180) convert E; [2180,2692) convert W.
// ---------------------------------------------------------------------------
__global__ void prep_kernel(const float* __restrict__ E, const float* __restrict__ W,
                            bf16_t* __restrict__ Eb, bf16_t* __restrict__ Wb,
                            bf16_t* __restrict__ R) {
    const int b = blockIdx.x;
    if (b < 132) {                       // 132*256 = 33792 = 8*4224 exact
        int idx = b * 256 + threadIdx.x;
        int s = idx / R_STRIDE;
        int x = idx - s * R_STRIDE;
        int d = R_O0 + s - x;
        float v = 0.0f;
        if (d >= 0 && d < L_SER)
            v = powf((d == 0) ? 1e-8f : ((float)d * (1.0f / (float)L_SER) + 1e-8f), 0.2f);
        R[idx] = (bf16_t)v;
    } else if (b < 132 + 2048) {         // E: 2048*256*8 = 4194304 elems exact
        int idx = (b - 132) * 256 + threadIdx.x;
        const f32x4* s = (const f32x4*)E;
        f32x4 v0 = s[idx * 2], v1 = s[idx * 2 + 1];
        bf16x8 o;
        o[0] = (bf16_t)v0[0]; o[1] = (bf16_t)v0[1]; o[2] = (bf16_t)v0[2]; o[3] = (bf16_t)v0[3];
        o[4] = (bf16_t)v1[0]; o[5] = (bf16_t)v1[1]; o[6] = (bf16_t)v1[2]; o[7] = (bf16_t)v1[3];
        ((bf16x8*)Eb)[idx] = o;
    } else {                             // W: 512*256*8 = 1048576 elems exact
        int idx = (b - 2180) * 256 + threadIdx.x;
        const f32x4* s = (const f32x4*)W;
        f32x4 v0 = s[idx * 2], v1 = s[idx * 2 + 1];
        bf16x8 o;
        o[0] = (bf16_t)v0[0]; o[1] = (bf16_t)v0[1]; o[2] = (bf16_t)v0[2]; o[3] = (bf16_t)v0[3];
        o[4] = (bf16_t)v1[0]; o[5] = (bf16_t)v1[1]; o[6] = (bf16_t)v1[2]; o[7] = (bf16_t)v1[3];
        ((bf16x8*)Wb)[idx] = o;
    }
}

// ---------------------------------------------------------------------------
// tsum: Tsum = T0 + T1, bf16x8 vectorized. 4096*1024 elems = 524288 x bf16x8.
// ---------------------------------------------------------------------------
__global__ void tsum_kernel(const bf16_t* __restrict__ T0, const bf16_t* __restrict__ T1,
                            bf16_t* __restrict__ Tsum) {
    int idx = blockIdx.x * 256 + threadIdx.x;     // 2048 blocks x 256 = 524288
    bf16x8 t0 = ((const bf16x8*)T0)[idx];
    bf16x8 t1 = ((const bf16x8*)T1)[idx];
    bf16x8 o;
#pragma unroll
    for (int u = 0; u < 8; ++u) o[u] = (bf16_t)((float)t0[u] + (float)t1[u]);
    ((bf16x8*)Tsum)[idx] = o;
}

// ---------------------------------------------------------------------------
// gemm_a: BM=128, BN=128, BK=64, split-j. 512 blocks (2/CU). Double-buffered
// LDS, one barrier per K-step, width-16 global_load_lds staging.
// DIAGNOSTIC: rep-loop runs the pipeline twice into the same acc.
// ---------------------------------------------------------------------------
#define GA_STAGE(SBOFS)                                                      \
    _Pragma("unroll")                                                        \
    for (int c = 0; c < 4; ++c) {                                            \
        glds16(pA[c], &sA[(SBOFS) + (c * 32 + wave * 8) * 64]);              \
        glds16(pB[c], &sB[(SBOFS) + (c * 32 + wave * 8) * 64]);              \
        pA[c] += 64; pB[c] += 64;                                            \
    }

#define GA_COMPUTE(SBOFS)                                                    \
    _Pragma("unroll")                                                        \
    for (int kk = 0; kk < 2; ++kk) {                                         \
        const int co = kk ? coff1 : coff0;                                   \
        bf16x8 afr[4], bfr[4];                                               \
        _Pragma("unroll")                                                    \
        for (int tm = 0; tm < 4; ++tm)                                       \
            afr[tm] = *(const bf16x8*)&sA[(SBOFS) + (wm * 64 + tm * 16 + ln) * 64 + co]; \
        _Pragma("unroll")                                                    \
        for (int tn = 0; tn < 4; ++tn)                                       \
            bfr[tn] = *(const bf16x8*)&sB[(SBOFS) + (wn * 64 + tn * 16 + ln) * 64 + co]; \
        _Pragma("unroll")                                                    \
        for (int tm = 0; tm < 4; ++tm)                                       \
            _Pragma("unroll")                                                \
            for (int tn = 0; tn < 4; ++tn)                                   \
                acc[tm][tn] = __builtin_amdgcn_mfma_f32_16x16x32_bf16(afr[tm], bfr[tn], acc[tm][tn], 0, 0, 0); \
    }

__global__ __launch_bounds__(256, 2) void gemm_a_kernel(const bf16_t* __restrict__ R,
                                                        const bf16_t* __restrict__ Eb,
                                                        bf16_t* __restrict__ T0,
                                                        bf16_t* __restrict__ T1) {
    __shared__ __align__(16) bf16_t sA[2 * 128 * 64];   // 32 KB
    __shared__ __align__(16) bf16_t sB[2 * 128 * 64];   // 32 KB

    const int bid = blockIdx.x;
    int I, nb, h;
    if (bid < 256) { I = bid >> 3;                nb = bid & 7;         h = 0; }
    else           { I = 31 - ((bid - 256) >> 3); nb = (bid - 256) & 7; h = 1; }
    const int i0 = I * 128;
    const int n0 = nb * 128;
    const int nsteps = I + 1;
    const int j0b = h ? 64 * (I + 1) : 0;
    bf16_t* __restrict__ Tout = h ? T1 : T0;

    const int tid  = threadIdx.x;
    const int wave = tid >> 6;
    const int lane = tid & 63;
    const int quad = lane >> 4;
    const int ln   = lane & 15;
    const int wm   = wave >> 1;
    const int wn   = wave & 1;

    // staging lane decomposition: row-in-group = lane>>3, swizzled chunk
    const int lrow = lane >> 3;                 // 0..7
    const int lch  = (lane & 7) ^ lrow;         // source chunk (0..7), XOR swizzle
    // fragment-read swizzled chunk offsets (elems): chunk = (kk*4+quad) ^ (row&7)
    const int rsw   = ln & 7;                   // row&7 for all fragment rows
    const int coff0 = ((quad ^ rsw)) * 8;       // kk = 0
    const int coff1 = (((4 + quad) ^ rsw)) * 8; // kk = 1

    f32x4 acc[4][4];
#pragma unroll
    for (int a = 0; a < 4; ++a)
#pragma unroll
        for (int b = 0; b < 4; ++b) acc[a][b] = (f32x4){0, 0, 0, 0};

    // DIAGNOSTIC rep-loop: run the whole K-pipeline twice, accumulate both
    // passes (acc ends at exactly 2*T), epilogue scales by 0.5.
    for (int rep = 0; rep < 2; ++rep) {
        // A row r: replica s=r&7, back-off 8*(r>>3):
        //   elem (r, col) at step j0 = R[s][R_O0 - (i0-j0) - 8*(r>>3) + col]
        const bf16_t* pA[4];
        const bf16_t* pB[4];
#pragma unroll
        for (int c = 0; c < 4; ++c) {
            int r = c * 32 + wave * 8 + lrow;
            pA[c] = R + (size_t)(r & 7) * R_STRIDE + (R_O0 - i0 + j0b - 8 * (r >> 3) + lch * 8);
            pB[c] = Eb + (size_t)(n0 + r) * L_SER + j0b + lch * 8;
        }

        __syncthreads();                             // WAR: buf0 may still be read
        GA_STAGE(0)                                  // step 0 -> buf0
        for (int s = 0;; s += 2) {
            __syncthreads();                         // drains buf0 stage
            if (s + 1 < nsteps) { GA_STAGE(128 * 64) }
            GA_COMPUTE(0)
            if (s + 1 >= nsteps) break;
            __syncthreads();                         // drains buf1 stage
            if (s + 2 < nsteps) { GA_STAGE(0) }
            GA_COMPUTE(128 * 64)
            if (s + 2 >= nsteps) break;
        }
    }

    // C/D: col = ln, row = quad*4 + r (m89-verified)
#pragma unroll
    for (int tm = 0; tm < 4; ++tm) {
        int row_base = i0 + wm * 64 + tm * 16 + quad * 4;
#pragma unroll
        for (int tn = 0; tn < 4; ++tn) {
            int col = n0 + wn * 64 + tn * 16 + ln;
#pragma unroll
            for (int r = 0; r < 4; ++r)
                Tout[(size_t)(row_base + r) * DEMB + col] = (bf16_t)(0.5f * acc[tm][tn][r]);
        }
    }
}

// ---------------------------------------------------------------------------
// gemm_b: out[i,v] = sum_e Tsum[i,e] * W[v,e]. BM=64, BN=128, BK=64, K=1024.
// 512 blocks (2/CU). BOTH operands via width-16 global_load_lds (swizzled
// source) -- zero per-step VALU beyond address upkeep.
// ---------------------------------------------------------------------------
#define GB_STAGE(AOFS, BOFS)                                                 \
    _Pragma("unroll")                                                        \
    for (int c = 0; c < 2; ++c) {                                            \
        glds16(pT[c], &sA[(AOFS) + (c * 32 + wave * 8) * 64]);               \
        pT[c] += 64;                                                         \
    }                                                                        \
    _Pragma("unroll")                                                        \
    for (int c = 0; c < 4; ++c) {                                            \
        glds16(pW[c], &sB[(BOFS) + (c * 32 + wave * 8) * 64]);               \
        pW[c] += 64;                                                         \
    }

#define GB_COMPUTE(AOFS, BOFS)                                               \
    _Pragma("unroll")                                                        \
    for (int kk = 0; kk < 2; ++kk) {                                         \
        const int co = kk ? coff1 : coff0;                                   \
        bf16x8 afr[2], bfr[4];                                               \
        _Pragma("unroll")                                                    \
        for (int tm = 0; tm < 2; ++tm)                                       \
            afr[tm] = *(const bf16x8*)&sA[(AOFS) + (wm * 32 + tm * 16 + ln) * 64 + co]; \
        _Pragma("unroll")                                                    \
        for (int tn = 0; tn < 4; ++tn)                                       \
            bfr[tn] = *(const bf16x8*)&sB[(BOFS) + (wn * 64 + tn * 16 + ln) * 64 + co]; \
        _Pragma("unroll")                                                    \
        for (int tm = 0; tm < 2; ++tm)                                       \
            _Pragma("unroll")                                                \
            for (int tn = 0; tn < 4; ++tn)                                   \
                acc[tm][tn] = __builtin_amdgcn_mfma_f32_16x16x32_bf16(afr[tm], bfr[tn], acc[tm][tn], 0, 0, 0); \
    }

__global__ __launch_bounds__(256, 2) void gemm_b_kernel(const bf16_t* __restrict__ Tsum,
                                                        const bf16_t* __restrict__ Wb,
                                                        float* __restrict__ out) {
    __shared__ __align__(16) bf16_t sA[2 * 64 * 64];    // 16 KB
    __shared__ __align__(16) bf16_t sB[2 * 128 * 64];   // 32 KB

    const int bid = blockIdx.x;
    const int ib = bid >> 3;        // 0..63
    const int nb = bid & 7;
    const int i0 = ib * 64;
    const int n0 = nb * 128;

    const int tid  = threadIdx.x;
    const int wave = tid >> 6;
    const int lane = tid & 63;
    const int quad = lane >> 4;
    const int ln   = lane & 15;
    const int wm   = wave >> 1;     // 0..1 over 64 m
    const int wn   = wave & 1;      // 0..1 over 128 n

    const int lrow = lane >> 3;
    const int lch  = (lane & 7) ^ lrow;
    const int rsw   = ln & 7;
    const int coff0 = ((quad ^ rsw)) * 8;
    const int coff1 = (((4 + quad) ^ rsw)) * 8;

    f32x4 acc[2][4];
#pragma unroll
    for (int a = 0; a < 2; ++a)
#pragma unroll
        for (int b = 0; b < 4; ++b) acc[a][b] = (f32x4){0, 0, 0, 0};

    const int nsteps = DEMB / 64;   // 16 (even)

    const bf16_t* pT[2];
    const bf16_t* pW[4];
#pragma unroll
    for (int c = 0; c < 2; ++c)
        pT[c] = Tsum + (size_t)(i0 + c * 32 + wave * 8 + lrow) * DEMB + lch * 8;
#pragma unroll
    for (int c = 0; c < 4; ++c)
        pW[c] = Wb + (size_t)(n0 + c * 32 + wave * 8 + lrow) * DEMB + lch * 8;

    GB_STAGE(0, 0)                                // step 0 -> buf0
    for (int s = 0;; s += 2) {
        __syncthreads();                          // drains buf0 stage
        if (s + 1 < nsteps) { GB_STAGE(64 * 64, 128 * 64) }
        GB_COMPUTE(0, 0)
        if (s + 1 >= nsteps) break;
        __syncthreads();                          // drains buf1 stage
        if (s + 2 < nsteps) { GB_STAGE(0, 0) }
        GB_COMPUTE(64 * 64, 128 * 64)
        if (s + 2 >= nsteps) break;
    }

#pragma unroll
    for (int tm = 0; tm < 2; ++tm) {
        int row_base = i0 + wm * 32 + tm * 16 + quad * 4;
#pragma unroll
        for (int tn = 0; tn < 4; ++tn) {
            int col = n0 + wn * 64 + tn * 16 + ln;
#pragma unroll
            for (int r = 0; r < 4; ++r)
                out[(size_t)(row_base + r) * DV + col] = acc[tm][tn][r];
        }
    }
}

// ---------------------------------------------------------------------------
extern "C" void kernel_launch(void* const* d_in, const int* in_sizes, int n_in,
                              void* d_out, int out_size, void* d_ws, size_t ws_size,
                              hipStream_t stream) {
    const float* E = (const float*)d_in[0];   // (1024, 4096) f32
    const float* W = (const float*)d_in[1];   // (1024, 1024) f32
    float* out = (float*)d_out;               // (4096, 1024) f32

    char* ws = (char*)d_ws;
    bf16_t* Eb   = (bf16_t*)(ws);                               // 8 MB
    bf16_t* T0   = (bf16_t*)(ws + (size_t)8  * 1024 * 1024);    // 8 MB
    bf16_t* T1   = (bf16_t*)(ws + (size_t)16 * 1024 * 1024);    // 8 MB
    bf16_t* Tsum = (bf16_t*)(ws + (size_t)24 * 1024 * 1024);    // 8 MB
    bf16_t* Wb   = (bf16_t*)(ws + (size_t)32 * 1024 * 1024);    // 2 MB
    bf16_t* R    = (bf16_t*)(ws + (size_t)34 * 1024 * 1024);    // 66 KB

    prep_kernel<<<2692, 256, 0, stream>>>(E, W, Eb, Wb, R);
    gemm_a_kernel<<<512, 256, 0, stream>>>(R, Eb, T0, T1);
    tsum_kernel<<<2048, 256, 0, stream>>>(T0, T1, Tsum);
    gemm_b_kernel<<<512, 256, 0, stream>>>(Tsum, Wb, out);
}

// Round 6
// 129.262 us; speedup vs baseline: 1.1402x; 1.1402x over previous
//
#include <hip/hip_runtime.h>
#include <hip/hip_bf16.h>
#include <cstdint>
#include <cstddef>

// out = (A2 @ E^T) @ W^T, A2[i,j] = a[i-j] lower-tri Toeplitz,
//   a[d] = (d/4096 + 1e-8)^0.2, a[0] = 1e-8^0.2
// gemm_a: T[i,e] = sum_{j<=i} a[i-j] * E[e,j]  (tri, split-j -> T0 + T1)
// tsum:   Tsum = T0 + T1
// gemm_b: out[i,v] = sum_e Tsum[i,e] * W[v,e]
// Round 12: accounting closed by R11 diagnostic: poison fill ~44us (in timed
// window, untouchable) + prep ~6 + gemm_a ~36 + tsum ~4 + gemm_b ~30.
// gemm_b's BM=64xBN=128 tile was structurally half-efficient (16 MFMA/wave-
// step vs 32, same barrier+staging cost, 8192 block-steps for half the
// FLOPs). Rewritten as 128x128 tile, 256 blocks (1/CU, 4 waves), loop body
// byte-identical to the verified gemm_a macros. gemm_a diagnostic rep-loop
// reverted to single pass.

#define L_SER 4096
#define DEMB  1024
#define DV    1024

#define R_STRIDE 4224   // shift-replica stride of reversed a; 16B-aligned
#define R_O0     4096

typedef __bf16 bf16_t;
typedef __attribute__((ext_vector_type(8))) __bf16 bf16x8;
typedef __attribute__((ext_vector_type(4))) float f32x4;

// direct global->LDS async copy, 16B per lane (dest = uniform base + lane*16)
__device__ __forceinline__ void glds16(const bf16_t* g, bf16_t* l) {
    __builtin_amdgcn_global_load_lds(
        (const __attribute__((address_space(1))) unsigned int*)(const void*)g,
        (__attribute__((address_space(3))) unsigned int*)(void*)l,
        16, 0, 0);
}

// ---------------------------------------------------------------------------
// Fused prep: blocks [0,132) build R; [132,2180) convert E; [2180,2692) convert W.
// ---------------------------------------------------------------------------
__global__ void prep_kernel(const float* __restrict__ E, const float* __restrict__ W,
                            bf16_t* __restrict__ Eb, bf16_t* __restrict__ Wb,
                            bf16_t* __restrict__ R) {
    const int b = blockIdx.x;
    if (b < 132) {                       // 132*256 = 33792 = 8*4224 exact
        int idx = b * 256 + threadIdx.x;
        int s = idx / R_STRIDE;
        int x = idx - s * R_STRIDE;
        int d = R_O0 + s - x;
        float v = 0.0f;
        if (d >= 0 && d < L_SER)
            v = powf((d == 0) ? 1e-8f : ((float)d * (1.0f / (float)L_SER) + 1e-8f), 0.2f);
        R[idx] = (bf16_t)v;
    } else if (b < 132 + 2048) {         // E: 2048*256*8 = 4194304 elems exact
        int idx = (b - 132) * 256 + threadIdx.x;
        const f32x4* s = (const f32x4*)E;
        f32x4 v0 = s[idx * 2], v1 = s[idx * 2 + 1];
        bf16x8 o;
        o[0] = (bf16_t)v0[0]; o[1] = (bf16_t)v0[1]; o[2] = (bf16_t)v0[2]; o[3] = (bf16_t)v0[3];
        o[4] = (bf16_t)v1[0]; o[5] = (bf16_t)v1[1]; o[6] = (bf16_t)v1[2]; o[7] = (bf16_t)v1[3];
        ((bf16x8*)Eb)[idx] = o;
    } else {                             // W: 512*256*8 = 1048576 elems exact
        int idx = (b - 2180) * 256 + threadIdx.x;
        const f32x4* s = (const f32x4*)W;
        f32x4 v0 = s[idx * 2], v1 = s[idx * 2 + 1];
        bf16x8 o;
        o[0] = (bf16_t)v0[0]; o[1] = (bf16_t)v0[1]; o[2] = (bf16_t)v0[2]; o[3] = (bf16_t)v0[3];
        o[4] = (bf16_t)v1[0]; o[5] = (bf16_t)v1[1]; o[6] = (bf16_t)v1[2]; o[7] = (bf16_t)v1[3];
        ((bf16x8*)Wb)[idx] = o;
    }
}

// ---------------------------------------------------------------------------
// tsum: Tsum = T0 + T1, bf16x8 vectorized. 4096*1024 elems = 524288 x bf16x8.
// ---------------------------------------------------------------------------
__global__ void tsum_kernel(const bf16_t* __restrict__ T0, const bf16_t* __restrict__ T1,
                            bf16_t* __restrict__ Tsum) {
    int idx = blockIdx.x * 256 + threadIdx.x;     // 2048 blocks x 256 = 524288
    bf16x8 t0 = ((const bf16x8*)T0)[idx];
    bf16x8 t1 = ((const bf16x8*)T1)[idx];
    bf16x8 o;
#pragma unroll
    for (int u = 0; u < 8; ++u) o[u] = (bf16_t)((float)t0[u] + (float)t1[u]);
    ((bf16x8*)Tsum)[idx] = o;
}

// ---------------------------------------------------------------------------
// Shared 128x128 BK=64 loop machinery (verified in gemm_a since R1).
// LDS linear [row][64], XOR chunk swizzle on BOTH sides (rule 21).
// ---------------------------------------------------------------------------
#define GA_STAGE(SBOFS)                                                      \
    _Pragma("unroll")                                                        \
    for (int c = 0; c < 4; ++c) {                                            \
        glds16(pA[c], &sA[(SBOFS) + (c * 32 + wave * 8) * 64]);              \
        glds16(pB[c], &sB[(SBOFS) + (c * 32 + wave * 8) * 64]);              \
        pA[c] += 64; pB[c] += 64;                                            \
    }

#define GA_COMPUTE(SBOFS)                                                    \
    _Pragma("unroll")                                                        \
    for (int kk = 0; kk < 2; ++kk) {                                         \
        const int co = kk ? coff1 : coff0;                                   \
        bf16x8 afr[4], bfr[4];                                               \
        _Pragma("unroll")                                                    \
        for (int tm = 0; tm < 4; ++tm)                                       \
            afr[tm] = *(const bf16x8*)&sA[(SBOFS) + (wm * 64 + tm * 16 + ln) * 64 + co]; \
        _Pragma("unroll")                                                    \
        for (int tn = 0; tn < 4; ++tn)                                       \
            bfr[tn] = *(const bf16x8*)&sB[(SBOFS) + (wn * 64 + tn * 16 + ln) * 64 + co]; \
        _Pragma("unroll")                                                    \
        for (int tm = 0; tm < 4; ++tm)                                       \
            _Pragma("unroll")                                                \
            for (int tn = 0; tn < 4; ++tn)                                   \
                acc[tm][tn] = __builtin_amdgcn_mfma_f32_16x16x32_bf16(afr[tm], bfr[tn], acc[tm][tn], 0, 0, 0); \
    }

#define GA_LANES()                                                           \
    const int tid  = threadIdx.x;                                            \
    const int wave = tid >> 6;                                               \
    const int lane = tid & 63;                                               \
    const int quad = lane >> 4;                                              \
    const int ln   = lane & 15;                                              \
    const int wm   = wave >> 1;                                              \
    const int wn   = wave & 1;                                               \
    const int lrow = lane >> 3;                                              \
    const int lch  = (lane & 7) ^ lrow;                                      \
    const int rsw   = ln & 7;                                                \
    const int coff0 = ((quad ^ rsw)) * 8;                                    \
    const int coff1 = (((4 + quad) ^ rsw)) * 8;

#define GA_LOOP()                                                            \
    GA_STAGE(0)                                                              \
    for (int s = 0;; s += 2) {                                               \
        __syncthreads();                                                     \
        if (s + 1 < nsteps) { GA_STAGE(128 * 64) }                           \
        GA_COMPUTE(0)                                                        \
        if (s + 1 >= nsteps) break;                                          \
        __syncthreads();                                                     \
        if (s + 2 < nsteps) { GA_STAGE(0) }                                  \
        GA_COMPUTE(128 * 64)                                                 \
        if (s + 2 >= nsteps) break;                                          \
    }

// ---------------------------------------------------------------------------
// gemm_a: BM=128, BN=128, BK=64, split-j. 512 blocks (2/CU); pair (bid,bid+256)
// shares a CU -> per-CU work = (I+1) + (32-I) = 33 steps.
// ---------------------------------------------------------------------------
__global__ __launch_bounds__(256, 2) void gemm_a_kernel(const bf16_t* __restrict__ R,
                                                        const bf16_t* __restrict__ Eb,
                                                        bf16_t* __restrict__ T0,
                                                        bf16_t* __restrict__ T1) {
    __shared__ __align__(16) bf16_t sA[2 * 128 * 64];   // 32 KB
    __shared__ __align__(16) bf16_t sB[2 * 128 * 64];   // 32 KB

    const int bid = blockIdx.x;
    int I, nb, h;
    if (bid < 256) { I = bid >> 3;                nb = bid & 7;         h = 0; }
    else           { I = 31 - ((bid - 256) >> 3); nb = (bid - 256) & 7; h = 1; }
    const int i0 = I * 128;
    const int n0 = nb * 128;
    const int nsteps = I + 1;
    const int j0b = h ? 64 * (I + 1) : 0;
    bf16_t* __restrict__ Tout = h ? T1 : T0;

    GA_LANES()

    f32x4 acc[4][4];
#pragma unroll
    for (int a = 0; a < 4; ++a)
#pragma unroll
        for (int b = 0; b < 4; ++b) acc[a][b] = (f32x4){0, 0, 0, 0};

    // A row r: replica s=r&7, back-off 8*(r>>3):
    //   elem (r, col) at step j0 = R[s][R_O0 - (i0-j0) - 8*(r>>3) + col]
    const bf16_t* pA[4];
    const bf16_t* pB[4];
#pragma unroll
    for (int c = 0; c < 4; ++c) {
        int r = c * 32 + wave * 8 + lrow;
        pA[c] = R + (size_t)(r & 7) * R_STRIDE + (R_O0 - i0 + j0b - 8 * (r >> 3) + lch * 8);
        pB[c] = Eb + (size_t)(n0 + r) * L_SER + j0b + lch * 8;
    }

    GA_LOOP()

    // C/D: col = ln, row = quad*4 + r (m89-verified)
#pragma unroll
    for (int tm = 0; tm < 4; ++tm) {
        int row_base = i0 + wm * 64 + tm * 16 + quad * 4;
#pragma unroll
        for (int tn = 0; tn < 4; ++tn) {
            int col = n0 + wn * 64 + tn * 16 + ln;
#pragma unroll
            for (int r = 0; r < 4; ++r)
                Tout[(size_t)(row_base + r) * DEMB + col] = (bf16_t)acc[tm][tn][r];
        }
    }
}

// ---------------------------------------------------------------------------
// gemm_b: out[i,v] = sum_e Tsum[i,e] * W[v,e]. BM=128, BN=128, BK=64, K=1024.
// 256 blocks (1/CU, 4 waves), 16 uniform K-steps, loop body identical to
// gemm_a's verified macros (both operands via width-16 global_load_lds).
// ---------------------------------------------------------------------------
__global__ __launch_bounds__(256, 2) void gemm_b_kernel(const bf16_t* __restrict__ Tsum,
                                                        const bf16_t* __restrict__ Wb,
                                                        float* __restrict__ out) {
    __shared__ __align__(16) bf16_t sA[2 * 128 * 64];   // 32 KB
    __shared__ __align__(16) bf16_t sB[2 * 128 * 64];   // 32 KB

    const int bid = blockIdx.x;
    const int ib = bid >> 3;        // 0..31
    const int nb = bid & 7;
    const int i0 = ib * 128;
    const int n0 = nb * 128;

    GA_LANES()

    f32x4 acc[4][4];
#pragma unroll
    for (int a = 0; a < 4; ++a)
#pragma unroll
        for (int b = 0; b < 4; ++b) acc[a][b] = (f32x4){0, 0, 0, 0};

    const int nsteps = DEMB / 64;   // 16

    const bf16_t* pA[4];
    const bf16_t* pB[4];
#pragma unroll
    for (int c = 0; c < 4; ++c) {
        int r = c * 32 + wave * 8 + lrow;
        pA[c] = Tsum + (size_t)(i0 + r) * DEMB + lch * 8;
        pB[c] = Wb + (size_t)(n0 + r) * DEMB + lch * 8;
    }

    GA_LOOP()

#pragma unroll
    for (int tm = 0; tm < 4; ++tm) {
        int row_base = i0 + wm * 64 + tm * 16 + quad * 4;
#pragma unroll
        for (int tn = 0; tn < 4; ++tn) {
            int col = n0 + wn * 64 + tn * 16 + ln;
#pragma unroll
            for (int r = 0; r < 4; ++r)
                out[(size_t)(row_base + r) * DV + col] = acc[tm][tn][r];
        }
    }
}

// ---------------------------------------------------------------------------
extern "C" void kernel_launch(void* const* d_in, const int* in_sizes, int n_in,
                              void* d_out, int out_size, void* d_ws, size_t ws_size,
                              hipStream_t stream) {
    const float* E = (const float*)d_in[0];   // (1024, 4096) f32
    const float* W = (const float*)d_in[1];   // (1024, 1024) f32
    float* out = (float*)d_out;               // (4096, 1024) f32

    char* ws = (char*)d_ws;
    bf16_t* Eb   = (bf16_t*)(ws);                               // 8 MB
    bf16_t* T0   = (bf16_t*)(ws + (size_t)8  * 1024 * 1024);    // 8 MB
    bf16_t* T1   = (bf16_t*)(ws + (size_t)16 * 1024 * 1024);    // 8 MB
    bf16_t* Tsum = (bf16_t*)(ws + (size_t)24 * 1024 * 1024);    // 8 MB
    bf16_t* Wb   = (bf16_t*)(ws + (size_t)32 * 1024 * 1024);    // 2 MB
    bf16_t* R    = (bf16_t*)(ws + (size_t)34 * 1024 * 1024);    // 66 KB

    prep_kernel<<<2692, 256, 0, stream>>>(E, W, Eb, Wb, R);
    gemm_a_kernel<<<512, 256, 0, stream>>>(R, Eb, T0, T1);
    tsum_kernel<<<2048, 256, 0, stream>>>(T0, T1, Tsum);
    gemm_b_kernel<<<256, 256, 0, stream>>>(Tsum, Wb, out);
}

// Round 8
// 124.969 us; speedup vs baseline: 1.1794x; 1.0344x over previous
//
#include <hip/hip_runtime.h>
#include <hip/hip_bf16.h>
#include <cstdint>
#include <cstddef>

// out = (A2 @ E^T) @ W^T, A2[i,j] = a[i-j] lower-tri Toeplitz,
//   a[d] = (d/4096 + 1e-8)^0.2, a[0] = 1e-8^0.2
// gemm_a: T[i,e] = sum_{j<=i} a[i-j] * E[e,j]  (tri, split-j -> T0 + T1)
// gemm_b: out[i,v] = sum_e T0[i,e]*W[v,e] + sum_e T1[i,e]*W[v,e]
//         (dual-A-stream MFMA: the T0+T1 add is absorbed into the matrix
//          pipe; tsum pass and Tsum buffer deleted)
// Round 14: R7 bench was an infrastructure failure (container died twice);
// kernel never ran. Resubmitting the R7 source unchanged.
// Budget (closed): fill ~44 + prep ~6 + gemm_a ~36 + tsum ~4.5 + gemm_b ~30.
// New gemm_b: BM=64, BN=128, 512 blocks (2/CU), stages T0-tile + T1-tile as
// a 128-row A-LDS (gemm_a's exact verified staging shape) + 128-row W tile;
// 32 MFMA / 16 ds_reads per wave-step (ratio 32 FLOP/B vs old 21.8), B
// staged once, f32 accumulation of T0+T1 (one bf16 rounding removed).

#define L_SER 4096
#define DEMB  1024
#define DV    1024

#define R_STRIDE 4224   // shift-replica stride of reversed a; 16B-aligned
#define R_O0     4096

typedef __bf16 bf16_t;
typedef __attribute__((ext_vector_type(8))) __bf16 bf16x8;
typedef __attribute__((ext_vector_type(4))) float f32x4;

// direct global->LDS async copy, 16B per lane (dest = uniform base + lane*16)
__device__ __forceinline__ void glds16(const bf16_t* g, bf16_t* l) {
    __builtin_amdgcn_global_load_lds(
        (const __attribute__((address_space(1))) unsigned int*)(const void*)g,
        (__attribute__((address_space(3))) unsigned int*)(void*)l,
        16, 0, 0);
}

// ---------------------------------------------------------------------------
// Fused prep: blocks [0,132) build R; [132,2180) convert E; [2180,2692) convert W.
// ---------------------------------------------------------------------------
__global__ void prep_kernel(const float* __restrict__ E, const float* __restrict__ W,
                            bf16_t* __restrict__ Eb, bf16_t* __restrict__ Wb,
                            bf16_t* __restrict__ R) {
    const int b = blockIdx.x;
    if (b < 132) {                       // 132*256 = 33792 = 8*4224 exact
        int idx = b * 256 + threadIdx.x;
        int s = idx / R_STRIDE;
        int x = idx - s * R_STRIDE;
        int d = R_O0 + s - x;
        float v = 0.0f;
        if (d >= 0 && d < L_SER)
            v = powf((d == 0) ? 1e-8f : ((float)d * (1.0f / (float)L_SER) + 1e-8f), 0.2f);
        R[idx] = (bf16_t)v;
    } else if (b < 132 + 2048) {         // E: 2048*256*8 = 4194304 elems exact
        int idx = (b - 132) * 256 + threadIdx.x;
        const f32x4* s = (const f32x4*)E;
        f32x4 v0 = s[idx * 2], v1 = s[idx * 2 + 1];
        bf16x8 o;
        o[0] = (bf16_t)v0[0]; o[1] = (bf16_t)v0[1]; o[2] = (bf16_t)v0[2]; o[3] = (bf16_t)v0[3];
        o[4] = (bf16_t)v1[0]; o[5] = (bf16_t)v1[1]; o[6] = (bf16_t)v1[2]; o[7] = (bf16_t)v1[3];
        ((bf16x8*)Eb)[idx] = o;
    } else {                             // W: 512*256*8 = 1048576 elems exact
        int idx = (b - 2180) * 256 + threadIdx.x;
        const f32x4* s = (const f32x4*)W;
        f32x4 v0 = s[idx * 2], v1 = s[idx * 2 + 1];
        bf16x8 o;
        o[0] = (bf16_t)v0[0]; o[1] = (bf16_t)v0[1]; o[2] = (bf16_t)v0[2]; o[3] = (bf16_t)v0[3];
        o[4] = (bf16_t)v1[0]; o[5] = (bf16_t)v1[1]; o[6] = (bf16_t)v1[2]; o[7] = (bf16_t)v1[3];
        ((bf16x8*)Wb)[idx] = o;
    }
}

// ---------------------------------------------------------------------------
// Shared staging/lane machinery (verified since R1).
// LDS linear [row][64], XOR chunk swizzle on BOTH sides (rule 21).
// ---------------------------------------------------------------------------
#define GA_STAGE(SBOFS)                                                      \
    _Pragma("unroll")                                                        \
    for (int c = 0; c < 4; ++c) {                                            \
        glds16(pA[c], &sA[(SBOFS) + (c * 32 + wave * 8) * 64]);              \
        glds16(pB[c], &sB[(SBOFS) + (c * 32 + wave * 8) * 64]);              \
        pA[c] += 64; pB[c] += 64;                                            \
    }

#define GA_COMPUTE(SBOFS)                                                    \
    _Pragma("unroll")                                                        \
    for (int kk = 0; kk < 2; ++kk) {                                         \
        const int co = kk ? coff1 : coff0;                                   \
        bf16x8 afr[4], bfr[4];                                               \
        _Pragma("unroll")                                                    \
        for (int tm = 0; tm < 4; ++tm)                                       \
            afr[tm] = *(const bf16x8*)&sA[(SBOFS) + (wm * 64 + tm * 16 + ln) * 64 + co]; \
        _Pragma("unroll")                                                    \
        for (int tn = 0; tn < 4; ++tn)                                       \
            bfr[tn] = *(const bf16x8*)&sB[(SBOFS) + (wn * 64 + tn * 16 + ln) * 64 + co]; \
        _Pragma("unroll")                                                    \
        for (int tm = 0; tm < 4; ++tm)                                       \
            _Pragma("unroll")                                                \
            for (int tn = 0; tn < 4; ++tn)                                   \
                acc[tm][tn] = __builtin_amdgcn_mfma_f32_16x16x32_bf16(afr[tm], bfr[tn], acc[tm][tn], 0, 0, 0); \
    }

#define GA_LANES()                                                           \
    const int tid  = threadIdx.x;                                            \
    const int wave = tid >> 6;                                               \
    const int lane = tid & 63;                                               \
    const int quad = lane >> 4;                                              \
    const int ln   = lane & 15;                                              \
    const int wm   = wave >> 1;                                              \
    const int wn   = wave & 1;                                               \
    const int lrow = lane >> 3;                                              \
    const int lch  = (lane & 7) ^ lrow;                                      \
    const int rsw   = ln & 7;                                                \
    const int coff0 = ((quad ^ rsw)) * 8;                                    \
    const int coff1 = (((4 + quad) ^ rsw)) * 8;

// ---------------------------------------------------------------------------
// gemm_a: BM=128, BN=128, BK=64, split-j. 512 blocks (2/CU); pair (bid,bid+256)
// shares a CU -> per-CU work = (I+1) + (32-I) = 33 steps.
// ---------------------------------------------------------------------------
__global__ __launch_bounds__(256, 2) void gemm_a_kernel(const bf16_t* __restrict__ R,
                                                        const bf16_t* __restrict__ Eb,
                                                        bf16_t* __restrict__ T0,
                                                        bf16_t* __restrict__ T1) {
    __shared__ __align__(16) bf16_t sA[2 * 128 * 64];   // 32 KB
    __shared__ __align__(16) bf16_t sB[2 * 128 * 64];   // 32 KB

    const int bid = blockIdx.x;
    int I, nb, h;
    if (bid < 256) { I = bid >> 3;                nb = bid & 7;         h = 0; }
    else           { I = 31 - ((bid - 256) >> 3); nb = (bid - 256) & 7; h = 1; }
    const int i0 = I * 128;
    const int n0 = nb * 128;
    const int nsteps = I + 1;
    const int j0b = h ? 64 * (I + 1) : 0;
    bf16_t* __restrict__ Tout = h ? T1 : T0;

    GA_LANES()

    f32x4 acc[4][4];
#pragma unroll
    for (int a = 0; a < 4; ++a)
#pragma unroll
        for (int b = 0; b < 4; ++b) acc[a][b] = (f32x4){0, 0, 0, 0};

    // A row r: replica s=r&7, back-off 8*(r>>3):
    //   elem (r, col) at step j0 = R[s][R_O0 - (i0-j0) - 8*(r>>3) + col]
    const bf16_t* pA[4];
    const bf16_t* pB[4];
#pragma unroll
    for (int c = 0; c < 4; ++c) {
        int r = c * 32 + wave * 8 + lrow;
        pA[c] = R + (size_t)(r & 7) * R_STRIDE + (R_O0 - i0 + j0b - 8 * (r >> 3) + lch * 8);
        pB[c] = Eb + (size_t)(n0 + r) * L_SER + j0b + lch * 8;
    }

    GA_STAGE(0)                                  // step 0 -> buf0
    for (int s = 0;; s += 2) {
        __syncthreads();                         // drains buf0 stage
        if (s + 1 < nsteps) { GA_STAGE(128 * 64) }
        GA_COMPUTE(0)
        if (s + 1 >= nsteps) break;
        __syncthreads();                         // drains buf1 stage
        if (s + 2 < nsteps) { GA_STAGE(0) }
        GA_COMPUTE(128 * 64)
        if (s + 2 >= nsteps) break;
    }

    // C/D: col = ln, row = quad*4 + r (m89-verified)
#pragma unroll
    for (int tm = 0; tm < 4; ++tm) {
        int row_base = i0 + wm * 64 + tm * 16 + quad * 4;
#pragma unroll
        for (int tn = 0; tn < 4; ++tn) {
            int col = n0 + wn * 64 + tn * 16 + ln;
#pragma unroll
            for (int r = 0; r < 4; ++r)
                Tout[(size_t)(row_base + r) * DEMB + col] = (bf16_t)acc[tm][tn][r];
        }
    }
}

// ---------------------------------------------------------------------------
// gemm_b: BM=64, BN=128, BK=64, K=1024, dual A-stream (T0,T1). 512 blocks
// (2/CU). A-LDS rows 0..63 = T0 tile, rows 64..127 = T1 tile (gemm_a's exact
// 128-row staging pattern); per kk: 4 afr + 4 bfr reads, 16 MFMA (8 per
// stream) into acc[2][4].
// ---------------------------------------------------------------------------
#define GB_COMPUTE(SBOFS)                                                    \
    _Pragma("unroll")                                                        \
    for (int kk = 0; kk < 2; ++kk) {                                         \
        const int co = kk ? coff1 : coff0;                                   \
        bf16x8 afr[4], bfr[4];                                               \
        _Pragma("unroll")                                                    \
        for (int c = 0; c < 4; ++c)                                          \
            afr[c] = *(const bf16x8*)&sA[(SBOFS) + (((c >> 1) * 64) + wm * 32 + (c & 1) * 16 + ln) * 64 + co]; \
        _Pragma("unroll")                                                    \
        for (int tn = 0; tn < 4; ++tn)                                       \
            bfr[tn] = *(const bf16x8*)&sB[(SBOFS) + (wn * 64 + tn * 16 + ln) * 64 + co]; \
        _Pragma("unroll")                                                    \
        for (int t = 0; t < 2; ++t)                                          \
            _Pragma("unroll")                                                \
            for (int tn = 0; tn < 4; ++tn)                                   \
                acc[t][tn] = __builtin_amdgcn_mfma_f32_16x16x32_bf16(afr[t], bfr[tn], acc[t][tn], 0, 0, 0); \
        _Pragma("unroll")                                                    \
        for (int t = 0; t < 2; ++t)                                          \
            _Pragma("unroll")                                                \
            for (int tn = 0; tn < 4; ++tn)                                   \
                acc[t][tn] = __builtin_amdgcn_mfma_f32_16x16x32_bf16(afr[2 + t], bfr[tn], acc[t][tn], 0, 0, 0); \
    }

__global__ __launch_bounds__(256, 2) void gemm_b_kernel(const bf16_t* __restrict__ T0,
                                                        const bf16_t* __restrict__ T1,
                                                        const bf16_t* __restrict__ Wb,
                                                        float* __restrict__ out) {
    __shared__ __align__(16) bf16_t sA[2 * 128 * 64];   // 32 KB
    __shared__ __align__(16) bf16_t sB[2 * 128 * 64];   // 32 KB

    const int bid = blockIdx.x;
    const int ib = bid >> 3;        // 0..63
    const int nb = bid & 7;
    const int i0 = ib * 64;
    const int n0 = nb * 128;

    GA_LANES()

    f32x4 acc[2][4];
#pragma unroll
    for (int a = 0; a < 2; ++a)
#pragma unroll
        for (int b = 0; b < 4; ++b) acc[a][b] = (f32x4){0, 0, 0, 0};

    const int nsteps = DEMB / 64;   // 16 (even)

    // A staging: c=0,1 -> T0 rows (c&1)*32+..., LDS rows 0..63;
    //            c=2,3 -> T1 rows (c&1)*32+..., LDS rows 64..127.
    const bf16_t* pA[4];
    const bf16_t* pB[4];
#pragma unroll
    for (int c = 0; c < 4; ++c) {
        const bf16_t* base = (c < 2) ? T0 : T1;
        int rr = (c & 1) * 32 + wave * 8 + lrow;
        pA[c] = base + (size_t)(i0 + rr) * DEMB + lch * 8;
        pB[c] = Wb + (size_t)(n0 + c * 32 + wave * 8 + lrow) * DEMB + lch * 8;
    }

    GA_STAGE(0)                                  // step 0 -> buf0
    for (int s = 0;; s += 2) {
        __syncthreads();                         // drains buf0 stage
        if (s + 1 < nsteps) { GA_STAGE(128 * 64) }
        GB_COMPUTE(0)
        if (s + 1 >= nsteps) break;
        __syncthreads();                         // drains buf1 stage
        if (s + 2 < nsteps) { GA_STAGE(0) }
        GB_COMPUTE(128 * 64)
        if (s + 2 >= nsteps) break;
    }

#pragma unroll
    for (int t = 0; t < 2; ++t) {
        int row_base = i0 + wm * 32 + t * 16 + quad * 4;
#pragma unroll
        for (int tn = 0; tn < 4; ++tn) {
            int col = n0 + wn * 64 + tn * 16 + ln;
#pragma unroll
            for (int r = 0; r < 4; ++r)
                out[(size_t)(row_base + r) * DV + col] = acc[t][tn][r];
        }
    }
}

// ---------------------------------------------------------------------------
extern "C" void kernel_launch(void* const* d_in, const int* in_sizes, int n_in,
                              void* d_out, int out_size, void* d_ws, size_t ws_size,
                              hipStream_t stream) {
    const float* E = (const float*)d_in[0];   // (1024, 4096) f32
    const float* W = (const float*)d_in[1];   // (1024, 1024) f32
    float* out = (float*)d_out;               // (4096, 1024) f32

    char* ws = (char*)d_ws;
    bf16_t* Eb = (bf16_t*)(ws);                               // 8 MB
    bf16_t* T0 = (bf16_t*)(ws + (size_t)8  * 1024 * 1024);    // 8 MB
    bf16_t* T1 = (bf16_t*)(ws + (size_t)16 * 1024 * 1024);    // 8 MB
    bf16_t* Wb = (bf16_t*)(ws + (size_t)24 * 1024 * 1024);    // 2 MB
    bf16_t* R  = (bf16_t*)(ws + (size_t)26 * 1024 * 1024);    // 66 KB

    prep_kernel<<<2692, 256, 0, stream>>>(E, W, Eb, Wb, R);
    gemm_a_kernel<<<512, 256, 0, stream>>>(R, Eb, T0, T1);
    gemm_b_kernel<<<512, 256, 0, stream>>>(T0, T1, Wb, out);
}